// Round 6
// baseline (224.427 us; speedup 1.0000x reference)
//
#include <hip/hip_runtime.h>
#include <math.h>

// Problem geometry (fixed): B=8, C=4, H=W=256; 24 = B*3 slices per mask type.
#define HWTOT 65536
#define WD 256
#define NSL 24

// Workspace layout (bytes) — everything written before read; no memset needed.
static constexpr size_t OFF_ACC  = 0;                          // double loss accumulator
static constexpr size_t OFF_DONE = 8;                          // int done-counter
static constexpr size_t OFF_OR   = 64;                         // u32[2][24][8]
static constexpr size_t OFF_AND  = OFF_OR + 2 * NSL * 8 * 4;   // u32[2][24][8]
static constexpr size_t OFF_MASK = 4096;                       // 24*65536 u8 (bit0=P, bit1=T)
static constexpr size_t OFF_ERR  = OFF_MASK + (size_t)NSL * HWTOT;      // f16
static constexpr size_t OFF_BITS = OFF_ERR + (size_t)NSL * HWTOT * 2;   // u32[2][24][8][256]
// Column bitmaps: bit r of bits[f][s][k][w] = mask bit f at (row 32k+r, col w).

// ---------------- Kernel 1: masks + err ----------------
__global__ __launch_bounds__(256) void k_mask(
    const float* __restrict__ pS, const float* __restrict__ pT,
    unsigned char* __restrict__ mask, _Float16* __restrict__ err)
{
    int blk = blockIdx.x;
    int b   = blk >> 8;          // image 0..7
    int hw  = (blk & 255) * 256 + threadIdx.x;

    const float* ps = pS + (size_t)b * 4 * HWTOT + hw;
    float s0 = ps[0], s1 = ps[HWTOT], s2 = ps[2 * HWTOT], s3 = ps[3 * HWTOT];
    float mx = fmaxf(fmaxf(s0, s1), fmaxf(s2, s3));
    float e0 = expf(s0 - mx), e1 = expf(s1 - mx), e2 = expf(s2 - mx), e3 = expf(s3 - mx);
    float inv = 1.0f / (e0 + e1 + e2 + e3);

    const float* pt = pT + (size_t)b * 4 * HWTOT + hw;
    float t0 = pt[0], t1 = pt[HWTOT], t2 = pt[2 * HWTOT], t3 = pt[3 * HWTOT];
    int lab = 0; float bm = t0;
    if (t1 > bm) { bm = t1; lab = 1; }
    if (t2 > bm) { bm = t2; lab = 2; }
    if (t3 > bm) { bm = t3; lab = 3; }

    float pv[3] = { e1 * inv, e2 * inv, e3 * inv };
    #pragma unroll
    for (int cc = 0; cc < 3; ++cc) {
        int sl = b * 3 + cc;
        bool mp = pv[cc] > 0.5f;
        bool mt = (lab == cc + 1);
        mask[(size_t)sl * HWTOT + hw] = (unsigned char)((mp ? 1 : 0) | (mt ? 2 : 0));
        float tcv = mt ? 1.0f : 0.0f;
        float ev = (pv[cc] - tcv) * (pv[cc] - tcv);
        err[(size_t)sl * HWTOT + hw] = (_Float16)ev;
    }
}

// ---------------- Kernel 2: pack 32-row groups into bitmaps + OR/AND ----------
// Block = (slice s, rowgroup k). Thread = column. Coalesced byte loads; plain
// stores of the two bitmap words; block-reduced OR/AND for validity flags.
// Block (0,0) also zero-inits the loss accumulator + done counter.
__global__ __launch_bounds__(256) void k_pack(
    const unsigned char* __restrict__ mask, unsigned* __restrict__ bits,
    unsigned* __restrict__ orv, unsigned* __restrict__ andv,
    double* __restrict__ acc, int* __restrict__ done)
{
    int s = blockIdx.x;
    int k = blockIdx.y;
    int w = threadIdx.x;
    const unsigned char* m = mask + (size_t)s * HWTOT + k * 32 * WD + w;

    unsigned vp = 0, vt = 0;
    #pragma unroll
    for (int i = 0; i < 32; ++i) {
        unsigned v = m[i * WD];
        vp |= (v & 1u) << i;
        vt |= ((v >> 1) & 1u) << i;
    }
    bits[((size_t)(0 * NSL + s) * 8 + k) * WD + w] = vp;
    bits[((size_t)(1 * NSL + s) * 8 + k) * WD + w] = vt;

    unsigned op = vp, ap = vp, ot = vt, at = vt;
    #pragma unroll
    for (int i = 1; i < 64; i <<= 1) {
        op |= __shfl_xor(op, i); ap &= __shfl_xor(ap, i);
        ot |= __shfl_xor(ot, i); at &= __shfl_xor(at, i);
    }
    __shared__ unsigned ro[4][4];
    int wv = w >> 6;
    if ((w & 63) == 0) { ro[wv][0] = op; ro[wv][1] = ap; ro[wv][2] = ot; ro[wv][3] = at; }
    __syncthreads();
    if (w == 0) {
        unsigned OP = ro[0][0] | ro[1][0] | ro[2][0] | ro[3][0];
        unsigned AP = ro[0][1] & ro[1][1] & ro[2][1] & ro[3][1];
        unsigned OT = ro[0][2] | ro[1][2] | ro[2][2] | ro[3][2];
        unsigned AT = ro[0][3] & ro[1][3] & ro[2][3] & ro[3][3];
        orv [(0 * NSL + s) * 8 + k] = OP;  andv[(0 * NSL + s) * 8 + k] = AP;
        orv [(1 * NSL + s) * 8 + k] = OT;  andv[(1 * NSL + s) * 8 + k] = AT;
        if (s == 0 && k == 0) { *acc = 0.0; *done = 0; }
    }
}

// Branch-free vertical distance from column bitmap (statically indexed words).
__device__ __forceinline__ int vdist(const unsigned W[8], unsigned inv, int h)
{
    int dd = 512;
    #pragma unroll
    for (int k = 0; k < 8; ++k) {           // ascending: first hit = nearest below
        unsigned y = W[k] ^ inv;
        unsigned gate;
        if (k * 32 + 31 <= h)      gate = 0u;
        else if (k * 32 > h)       gate = 0xFFFFFFFFu;
        else                       gate = 0xFFFFFFFFu << ((h - k * 32) + 1);
        unsigned z = y & gate;
        int cand = k * 32 + (__ffs(z) - 1) - h;
        dd = (z && dd == 512) ? cand : dd;
    }
    int du = 512;
    #pragma unroll
    for (int k = 7; k >= 0; --k) {          // descending: first hit = nearest above
        unsigned y = W[k] ^ inv;
        unsigned gate;
        if (k * 32 >= h)           gate = 0u;
        else if (k * 32 + 32 <= h) gate = 0xFFFFFFFFu;
        else                       gate = (1u << (h - k * 32)) - 1u;
        unsigned z = y & gate;
        int cand = h - (k * 32 + 31 - __clz(z));
        du = (z && du == 512) ? cand : du;
    }
    return min(dd, du);
}

// ---------------- Kernel 3: vertical-from-bitmap + horizontal min + loss ------
__global__ __launch_bounds__(256) void k_row(
    const _Float16* __restrict__ err, const unsigned* __restrict__ bits,
    const unsigned* __restrict__ orv, const unsigned* __restrict__ andv,
    double* __restrict__ acc, int* __restrict__ done, float* __restrict__ out)
{
    int h  = blockIdx.x;        // row 0..255
    int s  = blockIdx.y;        // slice 0..23
    int jo = threadIdx.x;

    __shared__ float4 g2[768];
    __shared__ float  wred[4];

    const unsigned* bP = bits + (size_t)(0 * NSL + s) * 8 * WD;
    const unsigned* bT = bits + (size_t)(1 * NSL + s) * 8 * WD;
    unsigned WP[8], WT[8];
    #pragma unroll
    for (int k = 0; k < 8; ++k) { WP[k] = bP[k * WD + jo]; WT[k] = bT[k * WD + jo]; }

    int kh = h >> 5, r = h & 31;
    unsigned mywP = 0, mywT = 0;
    #pragma unroll
    for (int k = 0; k < 8; ++k) if (k == kh) { mywP = WP[k]; mywT = WT[k]; }
    bool selP = (mywP >> r) & 1;
    bool selT = (mywT >> r) & 1;

    int gcP = vdist(WP, selP ? 0xFFFFFFFFu : 0u, h);
    int gcT = vdist(WT, selT ? 0xFFFFFFFFu : 0u, h);

    bool validP, validT;
    {
        unsigned OP = 0, AP = 0xFFFFFFFFu, OT = 0, AT = 0xFFFFFFFFu;
        #pragma unroll
        for (int k = 0; k < 8; ++k) {
            OP |= orv[(0 * NSL + s) * 8 + k];  AP &= andv[(0 * NSL + s) * 8 + k];
            OT |= orv[(1 * NSL + s) * 8 + k];  AT &= andv[(1 * NSL + s) * 8 + k];
        }
        validP = (OP != 0u) && (AP != 0xFFFFFFFFu);
        validT = (OT != 0u) && (AT != 0xFFFFFFFFu);
    }

    float fP = (float)(gcP * gcP);
    float fT = (float)(gcT * gcT);
    g2[256 + jo] = make_float4(selP ? fP : 0.0f, selP ? 0.0f : fP,
                               selT ? fT : 0.0f, selT ? 0.0f : fT);
    float4 inf4 = make_float4(1e30f, 1e30f, 1e30f, 1e30f);
    g2[jo] = inf4;
    g2[512 + jo] = inf4;

    int gsp = validP ? gcP : 0;
    int gst = validT ? gcT : 0;
    int R = min(max(gsp, gst), 256);
    #pragma unroll
    for (int i = 1; i < 64; i <<= 1) R = max(R, __shfl_xor(R, i));

    float m1 = (float)(gsp * gsp);
    float m2 = (float)(gst * gst);
    __syncthreads();

    for (int dd = 1; dd < R; ++dd) {
        float4 L  = g2[256 + jo - dd];
        float4 Rv = g2[256 + jo + dd];
        float d2 = (float)(dd * dd);
        float c1 = fminf(selP ? L.x : L.y, selP ? Rv.x : Rv.y);
        float c2 = fminf(selT ? L.z : L.w, selT ? Rv.z : Rv.w);
        m1 = fminf(m1, c1 + d2);
        m2 = fminf(m2, c2 + d2);
    }

    size_t rbase = (size_t)s * HWTOT + h * WD + jo;
    float contrib = (float)err[rbase] * (m1 + m2);

    #pragma unroll
    for (int off = 32; off > 0; off >>= 1) contrib += __shfl_down(contrib, off);
    if ((jo & 63) == 0) wred[jo >> 6] = contrib;
    __syncthreads();
    if (jo == 0) {
        float bsum = wred[0] + wred[1] + wred[2] + wred[3];
        atomicAdd(acc, (double)bsum);
        __threadfence();
        int prev = atomicAdd(done, 1);
        if (prev == NSL * 256 - 1) {
            double total = atomicAdd(acc, 0.0);   // atomic read of final value
            out[0] = (float)log(total / (double)((size_t)NSL * HWTOT) + 1.0);
        }
    }
}

extern "C" void kernel_launch(void* const* d_in, const int* in_sizes, int n_in,
                              void* d_out, int out_size, void* d_ws, size_t ws_size,
                              hipStream_t stream)
{
    const float* pS = (const float*)d_in[0];
    const float* pT = (const float*)d_in[1];
    float* out = (float*)d_out;

    char* ws = (char*)d_ws;
    double*         acc   = (double*)(ws + OFF_ACC);
    int*            done  = (int*)(ws + OFF_DONE);
    unsigned*       orv   = (unsigned*)(ws + OFF_OR);
    unsigned*       andv  = (unsigned*)(ws + OFF_AND);
    unsigned char*  mask  = (unsigned char*)(ws + OFF_MASK);
    _Float16*       err   = (_Float16*)(ws + OFF_ERR);
    unsigned*       bits  = (unsigned*)(ws + OFF_BITS);

    k_mask <<<dim3(2048),     dim3(256), 0, stream>>>(pS, pT, mask, err);
    k_pack <<<dim3(NSL, 8),   dim3(256), 0, stream>>>(mask, bits, orv, andv, acc, done);
    k_row  <<<dim3(256, NSL), dim3(256), 0, stream>>>(err, bits, orv, andv, acc, done, out);
}

// Round 7
// 105.381 us; speedup vs baseline: 2.1297x; 2.1297x over previous
//
#include <hip/hip_runtime.h>
#include <math.h>

// Problem geometry (fixed): B=8, C=4, H=W=256; 24 = B*3 slices per mask type.
#define HWTOT 65536
#define WD 256
#define NSL 24

// Workspace layout (bytes) — everything written before read; no memset needed.
static constexpr size_t OFF_PART = 256;                                  // 6144 f32
static constexpr size_t OFF_MASK = 24832;                                // 24*65536 u8 (bit0=P, bit1=T)
static constexpr size_t OFF_ERR  = OFF_MASK + (size_t)NSL * HWTOT;       // f16
static constexpr size_t OFF_BITS = OFF_ERR + (size_t)NSL * HWTOT * 2;    // u32[2][24][8][256]
static constexpr size_t OFF_GC   = OFF_BITS + (size_t)2 * NSL * 8 * WD * 4; // u16[2][24][256][256]
// bits: bit r of bits[f][s][k][w] = mask bit f at (row 32k+r, col w).
// gc[f][s][h][w] = vertical L1 distance to nearest differing pixel in column
// (clamp 512), pre-zeroed when the slice is invalid (empty or full mask).

// ---------------- Kernel 1: masks + err ----------------
__global__ __launch_bounds__(256) void k_mask(
    const float* __restrict__ pS, const float* __restrict__ pT,
    unsigned char* __restrict__ mask, _Float16* __restrict__ err)
{
    int blk = blockIdx.x;
    int b   = blk >> 8;          // image 0..7
    int hw  = (blk & 255) * 256 + threadIdx.x;

    const float* ps = pS + (size_t)b * 4 * HWTOT + hw;
    float s0 = ps[0], s1 = ps[HWTOT], s2 = ps[2 * HWTOT], s3 = ps[3 * HWTOT];
    float mx = fmaxf(fmaxf(s0, s1), fmaxf(s2, s3));
    float e0 = expf(s0 - mx), e1 = expf(s1 - mx), e2 = expf(s2 - mx), e3 = expf(s3 - mx);
    float inv = 1.0f / (e0 + e1 + e2 + e3);

    const float* pt = pT + (size_t)b * 4 * HWTOT + hw;
    float t0 = pt[0], t1 = pt[HWTOT], t2 = pt[2 * HWTOT], t3 = pt[3 * HWTOT];
    int lab = 0; float bm = t0;
    if (t1 > bm) { bm = t1; lab = 1; }
    if (t2 > bm) { bm = t2; lab = 2; }
    if (t3 > bm) { bm = t3; lab = 3; }

    float pv[3] = { e1 * inv, e2 * inv, e3 * inv };
    #pragma unroll
    for (int cc = 0; cc < 3; ++cc) {
        int sl = b * 3 + cc;
        bool mp = pv[cc] > 0.5f;
        bool mt = (lab == cc + 1);
        mask[(size_t)sl * HWTOT + hw] = (unsigned char)((mp ? 1 : 0) | (mt ? 2 : 0));
        float tcv = mt ? 1.0f : 0.0f;
        float ev = (pv[cc] - tcv) * (pv[cc] - tcv);
        err[(size_t)sl * HWTOT + hw] = (_Float16)ev;
    }
}

// ---------------- Kernel 2: pack 32-row groups into column bitmaps ----------
__global__ __launch_bounds__(256) void k_pack(
    const unsigned char* __restrict__ mask, unsigned* __restrict__ bits)
{
    int s = blockIdx.x;
    int k = blockIdx.y;
    int w = threadIdx.x;
    const unsigned char* m = mask + (size_t)s * HWTOT + k * 32 * WD + w;

    unsigned vp = 0, vt = 0;
    #pragma unroll
    for (int i = 0; i < 32; ++i) {
        unsigned v = m[i * WD];
        vp |= (v & 1u) << i;
        vt |= ((v >> 1) & 1u) << i;
    }
    bits[((size_t)(0 * NSL + s) * 8 + k) * WD + w] = vp;
    bits[((size_t)(1 * NSL + s) * 8 + k) * WD + w] = vt;
}

// Per-field vertical distances for 32 rows of one column, from the 8-word
// column bitmap. All loops statically unrolled; kk is block-uniform.
__device__ __forceinline__ void vgc_field(
    const unsigned Y[8], bool valid, int kk, int w,
    unsigned short* __restrict__ gout)
{
    // own word (runtime-uniform kk -> select chain, stays in registers)
    unsigned wk = 0;
    #pragma unroll
    for (int j = 0; j < 8; ++j) if (j == kk) wk = Y[j];

    // nearest set/clear strictly below row 32*kk
    int ls = -1000, lc = -1000;
    #pragma unroll
    for (int j = 0; j < 8; ++j) {
        if (j < kk) {
            unsigned z = Y[j], zc = ~Y[j];
            ls = z  ? (32 * j + 31 - __clz(z))  : ls;
            lc = zc ? (32 * j + 31 - __clz(zc)) : lc;
        }
    }
    // pass 1 ascending: du = distance to nearest differing bit below
    unsigned dupk[16];
    #pragma unroll
    for (int r = 0; r < 32; ++r) {
        int h = 32 * kk + r;
        int b = (wk >> r) & 1;
        int du = min(h - (b ? lc : ls), 512);
        if (r & 1) dupk[r >> 1] |= (unsigned)du << 16;
        else       dupk[r >> 1]  = (unsigned)du;
        ls = b ? h : ls;
        lc = b ? lc : h;
    }
    // nearest set/clear strictly above row 32*kk+31
    int ns = 100000, nc = 100000;
    #pragma unroll
    for (int j = 7; j >= 0; --j) {
        if (j > kk) {
            unsigned z = Y[j], zc = ~Y[j];
            ns = z  ? (32 * j + (__ffs(z)  - 1)) : ns;
            nc = zc ? (32 * j + (__ffs(zc) - 1)) : nc;
        }
    }
    // pass 2 descending: dd = distance above; combine, apply validity, store
    #pragma unroll
    for (int r = 31; r >= 0; --r) {
        int h = 32 * kk + r;
        int b = (wk >> r) & 1;
        int dd = min((b ? nc : ns) - h, 512);
        unsigned pk = dupk[r >> 1];
        int du = (r & 1) ? (int)(pk >> 16) : (int)(pk & 0xffffu);
        int gcv = min(du, dd);
        gcv = valid ? gcv : 0;
        gout[h * WD + w] = (unsigned short)gcv;   // coalesced per unrolled r
        ns = b ? h : ns;
        nc = b ? nc : h;
    }
}

// ---------------- Kernel 3: vertical distances from bitmaps ----------------
__global__ __launch_bounds__(256) void k_vgc(
    const unsigned* __restrict__ bits, unsigned short* __restrict__ gc)
{
    int s  = blockIdx.x;
    int kk = blockIdx.y;
    int w  = threadIdx.x;

    unsigned YP[8], YT[8];
    #pragma unroll
    for (int j = 0; j < 8; ++j) {
        YP[j] = bits[((size_t)(0 * NSL + s) * 8 + j) * WD + w];
        YT[j] = bits[((size_t)(1 * NSL + s) * 8 + j) * WD + w];
    }

    // slice-wide validity (any && !all) via block OR/AND reduce
    unsigned oP = 0, aP = 0xFFFFFFFFu, oT = 0, aT = 0xFFFFFFFFu;
    #pragma unroll
    for (int j = 0; j < 8; ++j) {
        oP |= YP[j]; aP &= YP[j];
        oT |= YT[j]; aT &= YT[j];
    }
    #pragma unroll
    for (int i = 1; i < 64; i <<= 1) {
        oP |= __shfl_xor(oP, i); aP &= __shfl_xor(aP, i);
        oT |= __shfl_xor(oT, i); aT &= __shfl_xor(aT, i);
    }
    __shared__ unsigned rb[4][4];
    if ((w & 63) == 0) {
        int wv = w >> 6;
        rb[wv][0] = oP; rb[wv][1] = aP; rb[wv][2] = oT; rb[wv][3] = aT;
    }
    __syncthreads();
    oP = rb[0][0] | rb[1][0] | rb[2][0] | rb[3][0];
    aP = rb[0][1] & rb[1][1] & rb[2][1] & rb[3][1];
    oT = rb[0][2] | rb[1][2] | rb[2][2] | rb[3][2];
    aT = rb[0][3] & rb[1][3] & rb[2][3] & rb[3][3];
    bool validP = (oP != 0u) && (aP != 0xFFFFFFFFu);
    bool validT = (oT != 0u) && (aT != 0xFFFFFFFFu);

    vgc_field(YP, validP, kk, w, gc + (size_t)(0 * NSL + s) * HWTOT);
    vgc_field(YT, validT, kk, w, gc + (size_t)(1 * NSL + s) * HWTOT);
}

// ---------------- Kernel 4: horizontal min, radius-limited, fused loss ------
__global__ __launch_bounds__(256) void k_row(
    const _Float16* __restrict__ err, const unsigned* __restrict__ bits,
    const unsigned short* __restrict__ gcArr, float* __restrict__ partials)
{
    int h  = blockIdx.x;        // row 0..255
    int s  = blockIdx.y;        // slice 0..23
    int jo = threadIdx.x;

    __shared__ float4 g2[768];
    __shared__ float  wred[4];

    size_t rbase = (size_t)s * HWTOT + h * WD + jo;
    int gcP = gcArr[rbase];
    int gcT = gcArr[(size_t)NSL * HWTOT + rbase];
    unsigned wP = bits[((size_t)(0 * NSL + s) * 8 + (h >> 5)) * WD + jo];
    unsigned wT = bits[((size_t)(1 * NSL + s) * 8 + (h >> 5)) * WD + jo];
    bool selP = (wP >> (h & 31)) & 1;
    bool selT = (wT >> (h & 31)) & 1;

    float fP = (float)(gcP * gcP);
    float fT = (float)(gcT * gcT);
    g2[256 + jo] = make_float4(selP ? fP : 0.0f, selP ? 0.0f : fP,
                               selT ? fT : 0.0f, selT ? 0.0f : fT);
    float4 inf4 = make_float4(1e30f, 1e30f, 1e30f, 1e30f);
    g2[jo] = inf4;
    g2[512 + jo] = inf4;

    int R = min(max(gcP, gcT), 256);
    #pragma unroll
    for (int i = 1; i < 64; i <<= 1) R = max(R, __shfl_xor(R, i));

    float m1 = fP;
    float m2 = fT;
    __syncthreads();

    for (int dd = 1; dd < R; ++dd) {
        float4 L  = g2[256 + jo - dd];
        float4 Rv = g2[256 + jo + dd];
        float d2 = (float)(dd * dd);
        float c1 = fminf(selP ? L.x : L.y, selP ? Rv.x : Rv.y);
        float c2 = fminf(selT ? L.z : L.w, selT ? Rv.z : Rv.w);
        m1 = fminf(m1, c1 + d2);
        m2 = fminf(m2, c2 + d2);
    }

    float contrib = (float)err[rbase] * (m1 + m2);

    #pragma unroll
    for (int off = 32; off > 0; off >>= 1) contrib += __shfl_down(contrib, off);
    if ((jo & 63) == 0) wred[jo >> 6] = contrib;
    __syncthreads();
    if (jo == 0) partials[s * 256 + h] = wred[0] + wred[1] + wred[2] + wred[3];
}

// ---------------- Kernel 5: final reduce (double) + log ----------------
__global__ __launch_bounds__(256) void k_final(
    const float* __restrict__ partials, float* __restrict__ out)
{
    __shared__ double red[256];
    int t = threadIdx.x;
    double acc = 0.0;
    for (int i = t; i < NSL * 256; i += 256) acc += (double)partials[i];
    red[t] = acc;
    __syncthreads();
    for (int off = 128; off > 0; off >>= 1) {
        if (t < off) red[t] += red[t + off];
        __syncthreads();
    }
    if (t == 0) {
        double loss = red[0] / (double)((size_t)NSL * HWTOT);
        out[0] = (float)log(loss + 1.0);
    }
}

extern "C" void kernel_launch(void* const* d_in, const int* in_sizes, int n_in,
                              void* d_out, int out_size, void* d_ws, size_t ws_size,
                              hipStream_t stream)
{
    const float* pS = (const float*)d_in[0];
    const float* pT = (const float*)d_in[1];
    float* out = (float*)d_out;

    char* ws = (char*)d_ws;
    float*          parts = (float*)(ws + OFF_PART);
    unsigned char*  mask  = (unsigned char*)(ws + OFF_MASK);
    _Float16*       err   = (_Float16*)(ws + OFF_ERR);
    unsigned*       bits  = (unsigned*)(ws + OFF_BITS);
    unsigned short* gc    = (unsigned short*)(ws + OFF_GC);

    k_mask <<<dim3(2048),     dim3(256), 0, stream>>>(pS, pT, mask, err);
    k_pack <<<dim3(NSL, 8),   dim3(256), 0, stream>>>(mask, bits);
    k_vgc  <<<dim3(NSL, 8),   dim3(256), 0, stream>>>(bits, gc);
    k_row  <<<dim3(256, NSL), dim3(256), 0, stream>>>(err, bits, gc, parts);
    k_final<<<dim3(1),        dim3(256), 0, stream>>>(parts, out);
}